// Round 7
// baseline (283.784 us; speedup 1.0000x reference)
//
#include <hip/hip_runtime.h>

#define SCALE 0.0625f  // C^-0.5 = 1/16

typedef __attribute__((ext_vector_type(4))) float f32x4;
typedef __attribute__((ext_vector_type(8))) short s16x8;

__device__ __forceinline__ unsigned short f2bf(float x) {
    unsigned u = __float_as_uint(x);
    u = u + 0x7FFF + ((u >> 16) & 1);   // RNE; inputs finite
    return (unsigned short)(u >> 16);
}

// ---------------------------------------------------------------------------
// prep1: blocks 0..15  -> q[b,c] = TO[b] . Wq[c] + bq[c]
//        blocks 16..31 -> WvB = bf16(Wv)   (row-major [co][o])
// ---------------------------------------------------------------------------
__global__ __launch_bounds__(256) void prep1_kernel(
    const float* __restrict__ TO,    // [2,1024]
    const float* __restrict__ Wq,    // [256,1024]
    const float* __restrict__ bq,    // [256]
    const float* __restrict__ Wv,    // [256,256]
    float* __restrict__ qbuf,        // [2,256]
    unsigned short* __restrict__ WvB)// [256,256] bf16
{
    const int blk = blockIdx.x;
    const int t   = threadIdx.x;
    if (blk < 16) {
        const int b    = blk >> 3;
        const int rblk = blk & 7;
        const int wv = t >> 6, l = t & 63;
        const float4* Wq4 = (const float4*)Wq;
        const float4* TO4 = (const float4*)TO;
        for (int rr = 0; rr < 8; ++rr) {
            const int c = rblk * 32 + wv * 8 + rr;
            float acc = 0.f;
#pragma unroll
            for (int i = 0; i < 4; ++i) {
                float4 wq = Wq4[c * 256 + i * 64 + l];
                float4 tv = TO4[b * 256 + i * 64 + l];
                acc = fmaf(wq.x, tv.x, acc);
                acc = fmaf(wq.y, tv.y, acc);
                acc = fmaf(wq.z, tv.z, acc);
                acc = fmaf(wq.w, tv.w, acc);
            }
#pragma unroll
            for (int mask = 1; mask < 64; mask <<= 1)
                acc += __shfl_xor(acc, mask, 64);
            if (l == 0) qbuf[b * 256 + c] = acc + bq[c];
        }
    } else {
        const int idx = blk - 16;   // 0..15, 4096 elements each
#pragma unroll
        for (int i = 0; i < 4; ++i) {
            const int e = idx * 4096 + i * 1024 + t * 4;
            const float4 f = ((const float4*)Wv)[e >> 2];
            ushort4 o;
            o.x = f2bf(f.x); o.y = f2bf(f.y);
            o.z = f2bf(f.z); o.w = f2bf(f.w);
            *(ushort4*)(WvB + e) = o;
        }
    }
}

// ---------------------------------------------------------------------------
// prep2: 16 blocks: qks[b,cp] = SCALE * sum_c q[c] Wk[c][cp]
// (q.bk term dropped: softmax-invariant)
// ---------------------------------------------------------------------------
__global__ __launch_bounds__(256) void prep2_kernel(
    const float* __restrict__ qbuf,  // [2,256]
    const float* __restrict__ Wk,    // [256,256]
    float* __restrict__ qks)         // [2,256] (pre-scaled)
{
    const int blk = blockIdx.x;
    const int t   = threadIdx.x;
    const int b = blk >> 3, j = blk & 7;
    const int col = t & 31, chunk = t >> 5;
    const int cp = j * 32 + col;
    float partial = 0.f;
#pragma unroll 8
    for (int cc = 0; cc < 32; ++cc) {
        const int c = chunk * 32 + cc;
        partial = fmaf(qbuf[b * 256 + c], Wk[c * 256 + cp], partial);
    }
    __shared__ float r2[8][32];
    r2[chunk][col] = partial;
    __syncthreads();
    if (t < 32) {
        float s = 0.f;
#pragma unroll
        for (int k = 0; k < 8; ++k) s += r2[k][t];
        qks[b * 256 + j * 32 + t] = SCALE * s;
    }
}

// ---------------------------------------------------------------------------
// scores_part: 512 blocks = bm(32) x cc(8) x ph(2); 256 thr.
//   Block streams 32 contiguous 8KB half-rows of X (c = 32cc..32cc+31,
//   px = 2048ph..2048ph+2047). Each thread covers TWO float4 segments
//   (t and t+256) so the half-row is fully swept (R6 bug: only one was).
//   part[cc][bm][px] = sum_{c in chunk} qks[c] * X[bm,c,px]
// ---------------------------------------------------------------------------
__global__ __launch_bounds__(256) void scores_part_kernel(
    const float* __restrict__ X,      // [2,16,256,4096]
    const float* __restrict__ qks,    // [2,256]
    float* __restrict__ part)         // [8][32][4096]
{
    const int blk = blockIdx.x;
    const int bm  = blk >> 4;          // 0..31
    const int cc  = (blk >> 1) & 7;    // 0..7
    const int ph  = blk & 1;           // px half (2048 px)
    const int b   = bm >> 4;
    const int t   = threadIdx.x;

    const float4* __restrict__ X4 =
        (const float4*)X + bm * 262144 + cc * 32768 + ph * 512 + t;
    const float* __restrict__ qr = qks + b * 256 + cc * 32;

    float4 a[2][2];  // [seg][rot]
#pragma unroll
    for (int s = 0; s < 2; ++s)
#pragma unroll
        for (int r = 0; r < 2; ++r) a[s][r] = make_float4(0, 0, 0, 0);

#pragma unroll
    for (int c = 0; c < 32; c += 2) {
        const float4 x00 = X4[(c + 0) * 1024];
        const float4 x01 = X4[(c + 0) * 1024 + 256];
        const float4 x10 = X4[(c + 1) * 1024];
        const float4 x11 = X4[(c + 1) * 1024 + 256];
        const float q0 = qr[c + 0], q1 = qr[c + 1];
        a[0][0].x = fmaf(q0, x00.x, a[0][0].x);
        a[0][0].y = fmaf(q0, x00.y, a[0][0].y);
        a[0][0].z = fmaf(q0, x00.z, a[0][0].z);
        a[0][0].w = fmaf(q0, x00.w, a[0][0].w);
        a[1][0].x = fmaf(q0, x01.x, a[1][0].x);
        a[1][0].y = fmaf(q0, x01.y, a[1][0].y);
        a[1][0].z = fmaf(q0, x01.z, a[1][0].z);
        a[1][0].w = fmaf(q0, x01.w, a[1][0].w);
        a[0][1].x = fmaf(q1, x10.x, a[0][1].x);
        a[0][1].y = fmaf(q1, x10.y, a[0][1].y);
        a[0][1].z = fmaf(q1, x10.z, a[0][1].z);
        a[0][1].w = fmaf(q1, x10.w, a[0][1].w);
        a[1][1].x = fmaf(q1, x11.x, a[1][1].x);
        a[1][1].y = fmaf(q1, x11.y, a[1][1].y);
        a[1][1].z = fmaf(q1, x11.z, a[1][1].z);
        a[1][1].w = fmaf(q1, x11.w, a[1][1].w);
    }

    float4* __restrict__ P4 = (float4*)part + (cc * 32 + bm) * 1024 + ph * 512 + t;
    float4 s0, s1;
    s0.x = a[0][0].x + a[0][1].x;  s0.y = a[0][0].y + a[0][1].y;
    s0.z = a[0][0].z + a[0][1].z;  s0.w = a[0][0].w + a[0][1].w;
    s1.x = a[1][0].x + a[1][1].x;  s1.y = a[1][0].y + a[1][1].y;
    s1.z = a[1][0].z + a[1][1].z;  s1.w = a[1][0].w + a[1][1].w;
    P4[0]   = s0;
    P4[256] = s1;
}

// ---------------------------------------------------------------------------
// softmax: 32 blocks = b(2) x pxchunk(16); 256 thr, thread = 1 px.
//   s[m] = sum_cc part[cc][b*16+m][px]; probs = exp(s)/sum (max-free).
// ---------------------------------------------------------------------------
__global__ __launch_bounds__(256) void softmax_kernel(
    const float* __restrict__ part,   // [8][32][4096]
    float* __restrict__ probs)        // [2][16][4096]
{
    const int blk = blockIdx.x;
    const int b   = blk >> 4;
    const int px  = ((blk & 15) << 8) + threadIdx.x;
    float e[16];
    float tot = 0.f;
#pragma unroll
    for (int m = 0; m < 16; ++m) {
        float s = 0.f;
#pragma unroll
        for (int cc = 0; cc < 8; ++cc)
            s += part[(cc * 32 + b * 16 + m) * 4096 + px];
        e[m] = __expf(s);
        tot += e[m];
    }
    const float inv = 1.0f / tot;
#pragma unroll
    for (int m = 0; m < 16; ++m)
        probs[(b * 16 + m) * 4096 + px] = e[m] * inv;
}

// ---------------------------------------------------------------------------
// wx: 256 blocks = b(2) x cpair(128); 256 thr.
//   wx[c,px] = sum_m probs[b,m,px] * X[b,m,c,px] for c in {2cp, 2cp+1}.
//   Block reads full 16KB rows (2 c-rows x 16 m); double-buffered over m,
//   zero barriers; probs L2-hot; writes full coalesced wx rows.
// ---------------------------------------------------------------------------
__global__ __launch_bounds__(256) void wx_kernel(
    const float* __restrict__ X,      // [2,16,256,4096]
    const float* __restrict__ probs,  // [2][16][4096]
    float* __restrict__ wxg)          // [2][256][4096]
{
    const int blk = blockIdx.x;
    const int b   = blk >> 7;
    const int cp  = blk & 127;
    const int t   = threadIdx.x;

    const float4* __restrict__ X4 = (const float4*)X;
    const float4* __restrict__ P4 = (const float4*)probs;

    const int xbase = b * 16 * 262144 + 2 * cp * 1024 + t;
    const int pbase = b * 16 * 1024 + t;

    float4 wxa[2][4];
#pragma unroll
    for (int ci = 0; ci < 2; ++ci)
#pragma unroll
        for (int sg = 0; sg < 4; ++sg) wxa[ci][sg] = make_float4(0,0,0,0);

    float4 v[2][2][4];   // [buf][ci][seg]
    float4 pv[2][4];     // [buf][seg]
#pragma unroll
    for (int sg = 0; sg < 4; ++sg) {
        v[0][0][sg] = X4[xbase + 0 * 1024 + sg * 256];
        v[0][1][sg] = X4[xbase + 1 * 1024 + sg * 256];
        pv[0][sg]   = P4[pbase + sg * 256];
    }

#pragma unroll
    for (int m = 0; m < 16; ++m) {
        const int buf = m & 1, nxt = buf ^ 1;
        if (m < 15) {
#pragma unroll
            for (int sg = 0; sg < 4; ++sg) {
                v[nxt][0][sg] = X4[xbase + (m + 1) * 262144 + 0 * 1024 + sg * 256];
                v[nxt][1][sg] = X4[xbase + (m + 1) * 262144 + 1 * 1024 + sg * 256];
                pv[nxt][sg]   = P4[pbase + (m + 1) * 1024 + sg * 256];
            }
        }
#pragma unroll
        for (int ci = 0; ci < 2; ++ci)
#pragma unroll
            for (int sg = 0; sg < 4; ++sg) {
                wxa[ci][sg].x = fmaf(pv[buf][sg].x, v[buf][ci][sg].x, wxa[ci][sg].x);
                wxa[ci][sg].y = fmaf(pv[buf][sg].y, v[buf][ci][sg].y, wxa[ci][sg].y);
                wxa[ci][sg].z = fmaf(pv[buf][sg].z, v[buf][ci][sg].z, wxa[ci][sg].z);
                wxa[ci][sg].w = fmaf(pv[buf][sg].w, v[buf][ci][sg].w, wxa[ci][sg].w);
            }
    }

    float4* __restrict__ W4 = (float4*)wxg;
#pragma unroll
    for (int ci = 0; ci < 2; ++ci)
#pragma unroll
        for (int sg = 0; sg < 4; ++sg)
            W4[(b * 256 + 2 * cp + ci) * 1024 + sg * 256 + t] = wxa[ci][sg];
}

// ---------------------------------------------------------------------------
// conv: 256 blocks = b(2) x px32-chunk(128); 512 thr (8 waves).
//   Stage wx[all c][32px] (L2/L3-hot) into LDS slab (stride 36), then the
//   verified bf16 MFMA epilogue: out[co,px] = bv[co] + sum_o Wv[co,o]wx[o,px]
// ---------------------------------------------------------------------------
__global__ __launch_bounds__(512, 1) void conv_kernel(
    const float* __restrict__ wxg,    // [2][256][4096]
    const unsigned short* __restrict__ WvB,  // [256,256] bf16
    const float* __restrict__ bv,     // [256]
    float* __restrict__ out)          // [2,256,4096]
{
    const int t   = threadIdx.x;
    const int blk = blockIdx.x;
    const int b   = blk >> 7;
    const int hw0 = (blk & 127) << 5;   // 32 pixels

    __shared__ float slab[256 * 36];

#pragma unroll
    for (int i = 0; i < 4; ++i) {
        const int idx = t + 512 * i;      // 0..2047
        const int c   = idx >> 3;
        const int px4 = idx & 7;
        const float4 v =
            ((const float4*)wxg)[(b * 256 + c) * 1024 + (hw0 >> 2) + px4];
        *(float4*)&slab[c * 36 + 4 * px4] = v;
    }
    __syncthreads();

    const int w    = t >> 6;          // wave 0..7
    const int ph   = w & 1;           // px half
    const int cot  = w >> 1;          // co-tile group
    const int lane = t & 63;
    const int pxl  = lane & 15;
    const int quad = lane >> 4;
    const int px   = 16 * ph + pxl;

    f32x4 acc[4];
#pragma unroll
    for (int i = 0; i < 4; ++i) {
        const int tt = 4 * cot + i;
#pragma unroll
        for (int r = 0; r < 4; ++r)
            acc[i][r] = bv[16 * tt + quad * 4 + r];
    }

#pragma unroll
    for (int ks = 0; ks < 8; ++ks) {   // K = 256 in steps of 32
        s16x8 bfr;
#pragma unroll
        for (int j = 0; j < 8; ++j)
            bfr[j] = (short)f2bf(slab[(ks * 32 + quad * 8 + j) * 36 + px]);
#pragma unroll
        for (int i = 0; i < 4; ++i) {
            const int tt = 4 * cot + i;
            const s16x8 afr =
                *(const s16x8*)(WvB + (16 * tt + pxl) * 256 + ks * 32 + quad * 8);
            acc[i] = __builtin_amdgcn_mfma_f32_16x16x32_bf16(afr, bfr, acc[i],
                                                             0, 0, 0);
        }
    }

    const int obase = b * 1048576 + hw0;
#pragma unroll
    for (int i = 0; i < 4; ++i) {
        const int tt = 4 * cot + i;
#pragma unroll
        for (int r = 0; r < 4; ++r) {
            const int co = 16 * tt + quad * 4 + r;
            out[obase + co * 4096 + px] = acc[i][r];
        }
    }
}

// ---------------------------------------------------------------------------
extern "C" void kernel_launch(void* const* d_in, const int* in_sizes, int n_in,
                              void* d_out, int out_size, void* d_ws, size_t ws_size,
                              hipStream_t stream) {
    const float* TO = (const float*)d_in[0];   // [2,1024]
    const float* X  = (const float*)d_in[1];   // [2,16,256,64,64]
    const float* Wq = (const float*)d_in[2];   // [256,1024]
    const float* bq = (const float*)d_in[3];   // [256]
    const float* Wk = (const float*)d_in[4];   // [256,256]
    // d_in[5] = bk: dropped (softmax-invariant)
    const float* Wv = (const float*)d_in[6];   // [256,256]
    const float* bv = (const float*)d_in[7];   // [256]
    float* out = (float*)d_out;
    float* ws  = (float*)d_ws;

    float*          qbuf  = ws;                             // 512 f
    float*          qks   = ws + 512;                       // 512 f
    unsigned short* WvB   = (unsigned short*)(ws + 1024);   // 65536 bf16 (32768 f)
    float*          part  = ws + 33792;                     // 1,048,576 f (4 MB)
    float*          probs = ws + 33792 + 1048576;           // 131,072 f
    float*          wxg   = ws + 33792 + 1048576 + 131072;  // 2,097,152 f (8 MB)

    hipLaunchKernelGGL(prep1_kernel, dim3(32), dim3(256), 0, stream,
                       TO, Wq, bq, Wv, qbuf, WvB);
    hipLaunchKernelGGL(prep2_kernel, dim3(16), dim3(256), 0, stream,
                       qbuf, Wk, qks);
    hipLaunchKernelGGL(scores_part_kernel, dim3(512), dim3(256), 0, stream,
                       X, qks, part);
    hipLaunchKernelGGL(softmax_kernel, dim3(32), dim3(256), 0, stream,
                       part, probs);
    hipLaunchKernelGGL(wx_kernel, dim3(256), dim3(256), 0, stream,
                       X, probs, wxg);
    hipLaunchKernelGGL(conv_kernel, dim3(256), dim3(512), 0, stream,
                       wxg, WvB, bv, out);
}